// Round 1
// baseline (608.110 us; speedup 1.0000x reference)
//
#include <hip/hip_runtime.h>
#include <hip/hip_bf16.h>

typedef __attribute__((ext_vector_type(8))) short bf16x8;
typedef __attribute__((ext_vector_type(4))) float f32x4;

__device__ __forceinline__ short f2b(float f) {
    unsigned u = __builtin_bit_cast(unsigned, f);
    unsigned r = (u + 0x7FFFu + ((u >> 16) & 1u)) >> 16;
    return (short)r;
}

// ---------- convert x (f32 -> bf16), vectorized ----------
__global__ void conv_bf4(const float* __restrict__ in, short* __restrict__ out, long n4) {
    long i = (long)blockIdx.x * blockDim.x + threadIdx.x;
    long stride = (long)gridDim.x * blockDim.x;
    for (; i < n4; i += stride) {
        float4 v = ((const float4*)in)[i];
        short4 o;
        o.x = f2b(v.x); o.y = f2b(v.y); o.z = f2b(v.z); o.w = f2b(v.w);
        ((short4*)out)[i] = o;
    }
}

// ---------- transpose + convert: in [R][C] f32 -> outT [C][R] bf16 ----------
__global__ void transpose_bf(const float* __restrict__ in, short* __restrict__ outT, int R, int C) {
    __shared__ float t[32][33];
    int c0 = blockIdx.x * 32, r0 = blockIdx.y * 32;
    int tx = threadIdx.x, ty = threadIdx.y; // 32 x 8
    #pragma unroll
    for (int j = 0; j < 4; ++j)
        t[ty + j * 8][tx] = in[(long)(r0 + ty + j * 8) * C + c0 + tx];
    __syncthreads();
    #pragma unroll
    for (int j = 0; j < 4; ++j)
        outT[(long)(c0 + ty + j * 8) * R + r0 + tx] = f2b(t[tx][ty + j * 8]);
}

// ---------- NT GEMM: C[M][N] = A[M][K] * Bt[N][K]^T, bf16 in, f32 acc ----------
// MODE 0: scatter z into qrole/krole/vT buffers (GEMM1). MODE 1: f32 out (GEMM2).
template<int MODE>
__launch_bounds__(256, 2)
__global__ void gemm_nt(const short* __restrict__ A, const short* __restrict__ Bt,
                        int M, int N, int K,
                        short* __restrict__ qrole, short* __restrict__ krole,
                        short* __restrict__ vT, float* __restrict__ out) {
    __shared__ __align__(16) short As[128][40];
    __shared__ __align__(16) short Bs[128][40];
    const int tid = threadIdx.x;
    const int lane = tid & 63;
    const int wid = tid >> 6;
    const int wm = wid >> 1, wn = wid & 1;
    const int m0 = blockIdx.y * 128, n0 = blockIdx.x * 128;
    const int r16 = lane & 15, g = lane >> 4;
    f32x4 acc[4][4] = {};
    for (int k0 = 0; k0 < K; k0 += 32) {
        for (int c = tid; c < 512; c += 256) {
            int row = c >> 2, kc = (c & 3) << 3;
            *(int4*)&As[row][kc] = *(const int4*)&A[(long)(m0 + row) * K + k0 + kc];
            *(int4*)&Bs[row][kc] = *(const int4*)&Bt[(long)(n0 + row) * K + k0 + kc];
        }
        __syncthreads();
        bf16x8 af[4], bfr[4];
        #pragma unroll
        for (int m = 0; m < 4; ++m) af[m] = *(const bf16x8*)&As[wm * 64 + m * 16 + r16][g * 8];
        #pragma unroll
        for (int n = 0; n < 4; ++n) bfr[n] = *(const bf16x8*)&Bs[wn * 64 + n * 16 + r16][g * 8];
        #pragma unroll
        for (int m = 0; m < 4; ++m)
            #pragma unroll
            for (int n = 0; n < 4; ++n)
                acc[m][n] = __builtin_amdgcn_mfma_f32_16x16x32_bf16(af[m], bfr[n], acc[m][n], 0, 0, 0);
        __syncthreads();
    }
    #pragma unroll
    for (int m = 0; m < 4; ++m) {
        #pragma unroll
        for (int n = 0; n < 4; ++n) {
            #pragma unroll
            for (int r = 0; r < 4; ++r) {
                int row = m0 + wm * 64 + m * 16 + g * 4 + r;
                int col = n0 + wn * 64 + n * 16 + r16;
                float v = acc[m][n][r];
                if (MODE == 0) {
                    int which = col >> 10, cc = col & 1023;
                    int h = cc >> 6, d = cc & 63;
                    int b = row >> 11, li = row & 2047;
                    int bh = b * 16 + h;
                    short bv = f2b(v);
                    if (which == 0)      qrole[((long)bh * 2048 + li) * 64 + d] = bv;
                    else if (which == 1) krole[((long)bh * 2048 + li) * 64 + d] = bv;
                    else                 vT[((long)bh * 64 + d) * 2048 + li] = bv;
                } else {
                    out[(long)row * N + col] = v;
                }
            }
        }
    }
}

// ---------- flash attention: Qrole=queries, Krole=keys, vT=[bh][64][L] ----------
__global__ void attn_kernel(const short* __restrict__ qrole, const short* __restrict__ krole,
                            const short* __restrict__ vT, short* __restrict__ y) {
    __shared__ __align__(16) short P_lds[4][16][72];
    const int tid = threadIdx.x;
    const int lane = tid & 63;
    const int w = tid >> 6;
    const int bh = blockIdx.y;
    const int q0 = blockIdx.x * 64;
    const int r16 = lane & 15, g = lane >> 4;
    const short* qb = qrole + (long)bh * 2048 * 64;
    const short* kb = krole + (long)bh * 2048 * 64;
    const short* vb = vT + (long)bh * 64 * 2048;
    const int iq = q0 + w * 16 + r16;
    bf16x8 qf[2];
    qf[0] = *(const bf16x8*)&qb[(long)iq * 64 + g * 8];
    qf[1] = *(const bf16x8*)&qb[(long)iq * 64 + 32 + g * 8];
    f32x4 o[4] = {};
    float mr[4], lr[4];
    #pragma unroll
    for (int r = 0; r < 4; ++r) { mr[r] = -1e30f; lr[r] = 0.f; }
    const int jend = q0 + 64;
    for (int jt = 0; jt < jend; jt += 64) {
        f32x4 s[4] = {};
        #pragma unroll
        for (int n = 0; n < 4; ++n) {
            int j = jt + n * 16 + r16;
            bf16x8 kf0 = *(const bf16x8*)&kb[(long)j * 64 + g * 8];
            bf16x8 kf1 = *(const bf16x8*)&kb[(long)j * 64 + 32 + g * 8];
            s[n] = __builtin_amdgcn_mfma_f32_16x16x32_bf16(qf[0], kf0, s[n], 0, 0, 0);
            s[n] = __builtin_amdgcn_mfma_f32_16x16x32_bf16(qf[1], kf1, s[n], 0, 0, 0);
        }
        #pragma unroll
        for (int r = 0; r < 4; ++r) {
            int i = q0 + w * 16 + g * 4 + r;
            float tm = -1e30f;
            #pragma unroll
            for (int n = 0; n < 4; ++n) {
                int j = jt + n * 16 + r16;
                float v = s[n][r] * 0.125f;
                v = (j > i) ? -1e30f : v;
                s[n][r] = v;
                tm = fmaxf(tm, v);
            }
            tm = fmaxf(tm, __shfl_xor(tm, 1));
            tm = fmaxf(tm, __shfl_xor(tm, 2));
            tm = fmaxf(tm, __shfl_xor(tm, 4));
            tm = fmaxf(tm, __shfl_xor(tm, 8));
            float mn = fmaxf(mr[r], tm);
            float sc = __expf(mr[r] - mn);
            float sum = 0.f;
            #pragma unroll
            for (int n = 0; n < 4; ++n) {
                float p = __expf(s[n][r] - mn);
                s[n][r] = p;
                sum += p;
            }
            sum += __shfl_xor(sum, 1);
            sum += __shfl_xor(sum, 2);
            sum += __shfl_xor(sum, 4);
            sum += __shfl_xor(sum, 8);
            lr[r] = lr[r] * sc + sum;
            mr[r] = mn;
            #pragma unroll
            for (int nd = 0; nd < 4; ++nd) o[nd][r] *= sc;
        }
        #pragma unroll
        for (int n = 0; n < 4; ++n)
            #pragma unroll
            for (int r = 0; r < 4; ++r)
                P_lds[w][g * 4 + r][n * 16 + r16] = f2b(s[n][r]);
        #pragma unroll
        for (int ks = 0; ks < 2; ++ks) {
            bf16x8 pf = *(const bf16x8*)&P_lds[w][r16][ks * 32 + g * 8];
            #pragma unroll
            for (int nd = 0; nd < 4; ++nd) {
                bf16x8 vf = *(const bf16x8*)&vb[(long)(nd * 16 + r16) * 2048 + jt + ks * 32 + g * 8];
                o[nd] = __builtin_amdgcn_mfma_f32_16x16x32_bf16(pf, vf, o[nd], 0, 0, 0);
            }
        }
    }
    const int b = bh >> 4, h = bh & 15;
    #pragma unroll
    for (int nd = 0; nd < 4; ++nd)
        #pragma unroll
        for (int r = 0; r < 4; ++r) {
            int li = q0 + w * 16 + g * 4 + r;
            float v = o[nd][r] / lr[r];
            y[((long)(b * 2048 + li)) * 1024 + h * 64 + nd * 16 + r16] = f2b(v);
        }
}

extern "C" void kernel_launch(void* const* d_in, const int* in_sizes, int n_in,
                              void* d_out, int out_size, void* d_ws, size_t ws_size,
                              hipStream_t stream) {
    const float* x  = (const float*)d_in[0];
    const float* Wa = (const float*)d_in[1];
    const float* Wf = (const float*)d_in[2];
    float* out = (float*)d_out;
    char* ws = (char*)d_ws;
    short* xb  = (short*)(ws);                   // 16 MB (8192x1024 bf16); reused as y
    short* wab = (short*)(ws + (16l << 20));     // 6 MB  (3072x1024 bf16, transposed)
    short* wfb = (short*)(ws + (22l << 20));     // 2 MB  (1024x1024 bf16, transposed)
    short* qr  = (short*)(ws + (24l << 20));     // 16 MB [B,H,L,64]
    short* kr  = (short*)(ws + (40l << 20));     // 16 MB [B,H,L,64]
    short* vt  = (short*)(ws + (56l << 20));     // 16 MB [B,H,64,L]

    conv_bf4<<<2048, 256, 0, stream>>>(x, xb, (long)8192 * 1024 / 4);
    transpose_bf<<<dim3(96, 32), dim3(32, 8), 0, stream>>>(Wa, wab, 1024, 3072);
    transpose_bf<<<dim3(32, 32), dim3(32, 8), 0, stream>>>(Wf, wfb, 1024, 1024);
    gemm_nt<0><<<dim3(24, 64), 256, 0, stream>>>(xb, wab, 8192, 3072, 1024, qr, kr, vt, nullptr);
    attn_kernel<<<dim3(32, 64), 256, 0, stream>>>(qr, kr, vt, xb);
    gemm_nt<1><<<dim3(8, 64), 256, 0, stream>>>(xb, wfb, 8192, 1024, 1024, nullptr, nullptr, nullptr, out);
}

// Round 2
// 512.678 us; speedup vs baseline: 1.1861x; 1.1861x over previous
//
#include <hip/hip_runtime.h>
#include <hip/hip_bf16.h>

typedef __attribute__((ext_vector_type(8))) short bf16x8;
typedef __attribute__((ext_vector_type(4))) float f32x4;

__device__ __forceinline__ short f2b(float f) {
    unsigned u = __builtin_bit_cast(unsigned, f);
    unsigned r = (u + 0x7FFFu + ((u >> 16) & 1u)) >> 16;
    return (short)r;
}

// ---------- convert x (f32 -> bf16), vectorized ----------
__global__ void conv_bf4(const float* __restrict__ in, short* __restrict__ out, long n4) {
    long i = (long)blockIdx.x * blockDim.x + threadIdx.x;
    long stride = (long)gridDim.x * blockDim.x;
    for (; i < n4; i += stride) {
        float4 v = ((const float4*)in)[i];
        short4 o;
        o.x = f2b(v.x); o.y = f2b(v.y); o.z = f2b(v.z); o.w = f2b(v.w);
        ((short4*)out)[i] = o;
    }
}

// ---------- transpose + convert: in [R][C] f32 -> outT [C][R] bf16 ----------
__global__ void transpose_bf(const float* __restrict__ in, short* __restrict__ outT, int R, int C) {
    __shared__ float t[32][33];
    int c0 = blockIdx.x * 32, r0 = blockIdx.y * 32;
    int tx = threadIdx.x, ty = threadIdx.y; // 32 x 8
    #pragma unroll
    for (int j = 0; j < 4; ++j)
        t[ty + j * 8][tx] = in[(long)(r0 + ty + j * 8) * C + c0 + tx];
    __syncthreads();
    #pragma unroll
    for (int j = 0; j < 4; ++j)
        outT[(long)(c0 + ty + j * 8) * R + r0 + tx] = f2b(t[tx][ty + j * 8]);
}

// ---------- NT GEMM: C[M][N] = A[M][K] * Bt[N][K]^T, bf16 in, f32 acc ----------
// MODE 0: scatter z into qrole/krole/vT buffers (GEMM1). MODE 1: f32 out (GEMM2).
template<int MODE>
__launch_bounds__(256, 2)
__global__ void gemm_nt(const short* __restrict__ A, const short* __restrict__ Bt,
                        int M, int N, int K,
                        short* __restrict__ qrole, short* __restrict__ krole,
                        short* __restrict__ vT, float* __restrict__ out) {
    __shared__ __align__(16) short As[128][40];
    __shared__ __align__(16) short Bs[128][40];
    const int tid = threadIdx.x;
    const int lane = tid & 63;
    const int wid = tid >> 6;
    const int wm = wid >> 1, wn = wid & 1;
    const int m0 = blockIdx.y * 128, n0 = blockIdx.x * 128;
    const int r16 = lane & 15, g = lane >> 4;
    f32x4 acc[4][4] = {};
    for (int k0 = 0; k0 < K; k0 += 32) {
        for (int c = tid; c < 512; c += 256) {
            int row = c >> 2, kc = (c & 3) << 3;
            *(int4*)&As[row][kc] = *(const int4*)&A[(long)(m0 + row) * K + k0 + kc];
            *(int4*)&Bs[row][kc] = *(const int4*)&Bt[(long)(n0 + row) * K + k0 + kc];
        }
        __syncthreads();
        bf16x8 af[4], bfr[4];
        #pragma unroll
        for (int m = 0; m < 4; ++m) af[m] = *(const bf16x8*)&As[wm * 64 + m * 16 + r16][g * 8];
        #pragma unroll
        for (int n = 0; n < 4; ++n) bfr[n] = *(const bf16x8*)&Bs[wn * 64 + n * 16 + r16][g * 8];
        #pragma unroll
        for (int m = 0; m < 4; ++m)
            #pragma unroll
            for (int n = 0; n < 4; ++n)
                acc[m][n] = __builtin_amdgcn_mfma_f32_16x16x32_bf16(af[m], bfr[n], acc[m][n], 0, 0, 0);
        __syncthreads();
    }
    #pragma unroll
    for (int m = 0; m < 4; ++m) {
        #pragma unroll
        for (int n = 0; n < 4; ++n) {
            #pragma unroll
            for (int r = 0; r < 4; ++r) {
                int row = m0 + wm * 64 + m * 16 + g * 4 + r;
                int col = n0 + wn * 64 + n * 16 + r16;
                float v = acc[m][n][r];
                if (MODE == 0) {
                    int which = col >> 10, cc = col & 1023;
                    int h = cc >> 6, d = cc & 63;
                    int b = row >> 11, li = row & 2047;
                    int bh = b * 16 + h;
                    if (which == 0)      qrole[((long)bh * 2048 + li) * 64 + d] = f2b(v * 0.125f);
                    else if (which == 1) krole[((long)bh * 2048 + li) * 64 + d] = f2b(v);
                    else                 vT[((long)bh * 64 + d) * 2048 + li] = f2b(v);
                } else {
                    out[(long)row * N + col] = v;
                }
            }
        }
    }
}

// ---------- flash attention, work-balanced (tiles t and 31-t per block) ----------
__global__ void attn_kernel(const short* __restrict__ qrole, const short* __restrict__ krole,
                            const short* __restrict__ vT, short* __restrict__ y) {
    __shared__ __align__(16) short P_lds[4][16][72];
    const int tid = threadIdx.x;
    const int lane = tid & 63;
    const int w = tid >> 6;
    const int bh = blockIdx.y;
    const int r16 = lane & 15, g = lane >> 4;
    const short* qb = qrole + (long)bh * 2048 * 64;
    const short* kb = krole + (long)bh * 2048 * 64;
    const short* vb = vT + (long)bh * 64 * 2048;
    const int b = bh >> 4, h = bh & 15;

    #pragma unroll
    for (int phase = 0; phase < 2; ++phase) {
        const int tile = (phase == 0) ? (int)blockIdx.x : 31 - (int)blockIdx.x;
        const int q0 = tile * 64;
        const int iq = q0 + w * 16 + r16;
        const bf16x8 qf0 = *(const bf16x8*)&qb[(long)iq * 64 + g * 8];
        const bf16x8 qf1 = *(const bf16x8*)&qb[(long)iq * 64 + 32 + g * 8];
        f32x4 o[4] = {};
        float mr[4], lr[4];
        #pragma unroll
        for (int r = 0; r < 4; ++r) { mr[r] = -1e30f; lr[r] = 0.f; }

        // prefetch K for jt=0
        bf16x8 kf[4][2];
        #pragma unroll
        for (int n = 0; n < 4; ++n) {
            kf[n][0] = *(const bf16x8*)&kb[(long)(n * 16 + r16) * 64 + g * 8];
            kf[n][1] = *(const bf16x8*)&kb[(long)(n * 16 + r16) * 64 + 32 + g * 8];
        }

        for (int jt = 0; jt <= q0; jt += 64) {
            // V for this tile (hidden under QK + softmax)
            bf16x8 vf[2][4];
            #pragma unroll
            for (int ks = 0; ks < 2; ++ks)
                #pragma unroll
                for (int nd = 0; nd < 4; ++nd)
                    vf[ks][nd] = *(const bf16x8*)&vb[(long)(nd * 16 + r16) * 2048 + jt + ks * 32 + g * 8];
            // K for next tile
            bf16x8 kn[4][2];
            if (jt < q0) {
                #pragma unroll
                for (int n = 0; n < 4; ++n) {
                    kn[n][0] = *(const bf16x8*)&kb[(long)(jt + 64 + n * 16 + r16) * 64 + g * 8];
                    kn[n][1] = *(const bf16x8*)&kb[(long)(jt + 64 + n * 16 + r16) * 64 + 32 + g * 8];
                }
            }
            // QK^T (q pre-scaled by 1/8 in GEMM1 epilogue)
            f32x4 s[4] = {};
            #pragma unroll
            for (int n = 0; n < 4; ++n) {
                s[n] = __builtin_amdgcn_mfma_f32_16x16x32_bf16(qf0, kf[n][0], s[n], 0, 0, 0);
                s[n] = __builtin_amdgcn_mfma_f32_16x16x32_bf16(qf1, kf[n][1], s[n], 0, 0, 0);
            }
            if (jt == q0) { // diagonal tile: mask j > i
                #pragma unroll
                for (int n = 0; n < 4; ++n)
                    #pragma unroll
                    for (int r = 0; r < 4; ++r)
                        if (n * 16 + r16 > w * 16 + g * 4 + r) s[n][r] = -1e30f;
            }
            // ---- softmax: local max + early exp overlapped with cross-lane max ----
            float tmloc[4], tm[4];
            #pragma unroll
            for (int r = 0; r < 4; ++r) {
                tmloc[r] = fmaxf(fmaxf(s[0][r], s[1][r]), fmaxf(s[2][r], s[3][r]));
                tm[r] = tmloc[r];
            }
            #pragma unroll
            for (int st = 1; st <= 8; st <<= 1)
                #pragma unroll
                for (int r = 0; r < 4; ++r)
                    tm[r] = fmaxf(tm[r], __shfl_xor(tm[r], st));
            float ps[4][4];
            #pragma unroll
            for (int n = 0; n < 4; ++n)
                #pragma unroll
                for (int r = 0; r < 4; ++r)
                    ps[n][r] = __expf(s[n][r] - tmloc[r]);
            float sloc[4], mn_[4], fct[4], sc[4], contrib[4];
            #pragma unroll
            for (int r = 0; r < 4; ++r) {
                sloc[r] = (ps[0][r] + ps[1][r]) + (ps[2][r] + ps[3][r]);
                mn_[r] = fmaxf(mr[r], tm[r]);
                fct[r] = __expf(tmloc[r] - mn_[r]);
                sc[r] = __expf(mr[r] - mn_[r]);
                contrib[r] = sloc[r] * fct[r];
            }
            #pragma unroll
            for (int st = 1; st <= 8; st <<= 1)
                #pragma unroll
                for (int r = 0; r < 4; ++r)
                    contrib[r] += __shfl_xor(contrib[r], st);
            #pragma unroll
            for (int r = 0; r < 4; ++r) {
                lr[r] = lr[r] * sc[r] + contrib[r];
                mr[r] = mn_[r];
            }
            #pragma unroll
            for (int nd = 0; nd < 4; ++nd)
                #pragma unroll
                for (int r = 0; r < 4; ++r)
                    o[nd][r] *= sc[r];
            // P -> LDS (wave-local)
            #pragma unroll
            for (int n = 0; n < 4; ++n)
                #pragma unroll
                for (int r = 0; r < 4; ++r)
                    P_lds[w][g * 4 + r][n * 16 + r16] = f2b(ps[n][r] * fct[r]);
            // PV
            #pragma unroll
            for (int ks = 0; ks < 2; ++ks) {
                bf16x8 pf = *(const bf16x8*)&P_lds[w][r16][ks * 32 + g * 8];
                #pragma unroll
                for (int nd = 0; nd < 4; ++nd)
                    o[nd] = __builtin_amdgcn_mfma_f32_16x16x32_bf16(pf, vf[ks][nd], o[nd], 0, 0, 0);
            }
            #pragma unroll
            for (int n = 0; n < 4; ++n) { kf[n][0] = kn[n][0]; kf[n][1] = kn[n][1]; }
        }
        // epilogue
        float inv[4];
        #pragma unroll
        for (int r = 0; r < 4; ++r) inv[r] = 1.0f / lr[r];
        #pragma unroll
        for (int nd = 0; nd < 4; ++nd)
            #pragma unroll
            for (int r = 0; r < 4; ++r) {
                int li = q0 + w * 16 + g * 4 + r;
                y[((long)(b * 2048 + li)) * 1024 + h * 64 + nd * 16 + r16] = f2b(o[nd][r] * inv[r]);
            }
    }
}

extern "C" void kernel_launch(void* const* d_in, const int* in_sizes, int n_in,
                              void* d_out, int out_size, void* d_ws, size_t ws_size,
                              hipStream_t stream) {
    const float* x  = (const float*)d_in[0];
    const float* Wa = (const float*)d_in[1];
    const float* Wf = (const float*)d_in[2];
    float* out = (float*)d_out;
    char* ws = (char*)d_ws;
    short* xb  = (short*)(ws);                   // 16 MB (8192x1024 bf16); reused as y
    short* wab = (short*)(ws + (16l << 20));     // 6 MB  (3072x1024 bf16, transposed)
    short* wfb = (short*)(ws + (22l << 20));     // 2 MB  (1024x1024 bf16, transposed)
    short* qr  = (short*)(ws + (24l << 20));     // 16 MB [B,H,L,64] (pre-scaled by 1/8)
    short* kr  = (short*)(ws + (40l << 20));     // 16 MB [B,H,L,64]
    short* vt  = (short*)(ws + (56l << 20));     // 16 MB [B,H,64,L]

    conv_bf4<<<2048, 256, 0, stream>>>(x, xb, (long)8192 * 1024 / 4);
    transpose_bf<<<dim3(96, 32), dim3(32, 8), 0, stream>>>(Wa, wab, 1024, 3072);
    transpose_bf<<<dim3(32, 32), dim3(32, 8), 0, stream>>>(Wf, wfb, 1024, 1024);
    gemm_nt<0><<<dim3(24, 64), 256, 0, stream>>>(xb, wab, 8192, 3072, 1024, qr, kr, vt, nullptr);
    attn_kernel<<<dim3(16, 64), 256, 0, stream>>>(qr, kr, vt, xb);
    gemm_nt<1><<<dim3(8, 64), 256, 0, stream>>>(xb, wfb, 8192, 1024, 1024, nullptr, nullptr, nullptr, out);
}

// Round 3
// 252.024 us; speedup vs baseline: 2.4129x; 2.0342x over previous
//
#include <hip/hip_runtime.h>
#include <hip/hip_bf16.h>

typedef __attribute__((ext_vector_type(8))) short bf16x8;
typedef __attribute__((ext_vector_type(4))) float f32x4;

__device__ __forceinline__ short f2b(float f) {
    unsigned u = __builtin_bit_cast(unsigned, f);
    unsigned r = (u + 0x7FFFu + ((u >> 16) & 1u)) >> 16;
    return (short)r;
}

__device__ __forceinline__ void gload_lds16(const void* g, void* l) {
    __builtin_amdgcn_global_load_lds((const __attribute__((address_space(1))) unsigned*)g,
                                     (__attribute__((address_space(3))) unsigned*)l, 16, 0, 0);
}

// ---------- convert x (f32 -> bf16), vectorized ----------
__global__ void conv_bf4(const float* __restrict__ in, short* __restrict__ out, long n4) {
    long i = (long)blockIdx.x * blockDim.x + threadIdx.x;
    long stride = (long)gridDim.x * blockDim.x;
    for (; i < n4; i += stride) {
        float4 v = ((const float4*)in)[i];
        short4 o;
        o.x = f2b(v.x); o.y = f2b(v.y); o.z = f2b(v.z); o.w = f2b(v.w);
        ((short4*)out)[i] = o;
    }
}

// ---------- transpose + convert: in [R][C] f32 -> outT [C][R] bf16 ----------
__global__ void transpose_bf(const float* __restrict__ in, short* __restrict__ outT, int R, int C) {
    __shared__ float t[32][33];
    int c0 = blockIdx.x * 32, r0 = blockIdx.y * 32;
    int tx = threadIdx.x, ty = threadIdx.y; // 32 x 8
    #pragma unroll
    for (int j = 0; j < 4; ++j)
        t[ty + j * 8][tx] = in[(long)(r0 + ty + j * 8) * C + c0 + tx];
    __syncthreads();
    #pragma unroll
    for (int j = 0; j < 4; ++j)
        outT[(long)(c0 + ty + j * 8) * R + r0 + tx] = f2b(t[tx][ty + j * 8]);
}

// ---------- NT GEMM: C[M][N] = A[M][K] * Bt[N][K]^T, bf16 in, f32 acc ----------
// MODE 0: scatter z into qrole/krole(swizzled)/vT(swizzled) (GEMM1). MODE 1: f32 out.
template<int MODE>
__launch_bounds__(256, 2)
__global__ void gemm_nt(const short* __restrict__ A, const short* __restrict__ Bt,
                        int M, int N, int K,
                        short* __restrict__ qrole, short* __restrict__ krole,
                        short* __restrict__ vT, float* __restrict__ out) {
    __shared__ __align__(16) short As[128][40];
    __shared__ __align__(16) short Bs[128][40];
    const int tid = threadIdx.x;
    const int lane = tid & 63;
    const int wid = tid >> 6;
    const int wm = wid >> 1, wn = wid & 1;
    const int m0 = blockIdx.y * 128, n0 = blockIdx.x * 128;
    const int r16 = lane & 15, g = lane >> 4;
    f32x4 acc[4][4] = {};
    for (int k0 = 0; k0 < K; k0 += 32) {
        for (int c = tid; c < 512; c += 256) {
            int row = c >> 2, kc = (c & 3) << 3;
            *(int4*)&As[row][kc] = *(const int4*)&A[(long)(m0 + row) * K + k0 + kc];
            *(int4*)&Bs[row][kc] = *(const int4*)&Bt[(long)(n0 + row) * K + k0 + kc];
        }
        __syncthreads();
        bf16x8 af[4], bfr[4];
        #pragma unroll
        for (int m = 0; m < 4; ++m) af[m] = *(const bf16x8*)&As[wm * 64 + m * 16 + r16][g * 8];
        #pragma unroll
        for (int n = 0; n < 4; ++n) bfr[n] = *(const bf16x8*)&Bs[wn * 64 + n * 16 + r16][g * 8];
        #pragma unroll
        for (int m = 0; m < 4; ++m)
            #pragma unroll
            for (int n = 0; n < 4; ++n)
                acc[m][n] = __builtin_amdgcn_mfma_f32_16x16x32_bf16(af[m], bfr[n], acc[m][n], 0, 0, 0);
        __syncthreads();
    }
    #pragma unroll
    for (int m = 0; m < 4; ++m) {
        #pragma unroll
        for (int n = 0; n < 4; ++n) {
            #pragma unroll
            for (int r = 0; r < 4; ++r) {
                int row = m0 + wm * 64 + m * 16 + g * 4 + r;
                int col = n0 + wn * 64 + n * 16 + r16;
                float v = acc[m][n][r];
                if (MODE == 0) {
                    int which = col >> 10, cc = col & 1023;
                    int h = cc >> 6, d = cc & 63;
                    int b = row >> 11, li = row & 2047;
                    int bh = b * 16 + h;
                    if (which == 0)      qrole[((long)bh * 2048 + li) * 64 + d] = f2b(v * 0.125f);
                    else if (which == 1) krole[((long)bh * 2048 + li) * 64 + (d ^ ((li & 7) << 3))] = f2b(v);
                    else                 vT[((long)bh * 64 + d) * 2048 + ((li & ~63) | ((li & 63) ^ ((d & 7) << 3)))] = f2b(v);
                } else {
                    out[(long)row * N + col] = v;
                }
            }
        }
    }
}

// ---------- flash attention: 256 q-rows/block, LDS-staged KV, swapped QK^T ----------
__launch_bounds__(256, 2)
__global__ void attn_kernel(const short* __restrict__ qrole, const short* __restrict__ krole,
                            const short* __restrict__ vT, short* __restrict__ y) {
    __shared__ __align__(16) short K_lds[2][64][64];
    __shared__ __align__(16) short V_lds[2][64][64];
    __shared__ __align__(16) short P_lds[4][16][72];
    const int tid = threadIdx.x, lane = tid & 63, w = tid >> 6;
    const int r16 = lane & 15, g = lane >> 4;
    const int wg = blockIdx.x;
    const int bh = wg & 63;            // id%8 == bh%8 -> one XCD per bh
    const int c = 7 - (wg >> 6);       // LPT: longest chunks dispatched first
    const int q0 = c << 8;
    const short* qb = qrole + (long)bh * (2048 * 64);
    const short* kb = krole + (long)bh * (2048 * 64);
    const short* vb = vT + (long)bh * (64 * 2048);

    // Q fragments in registers: wave w, frag m covers q rows q0 + m*64 + w*16 + [0,16)
    bf16x8 qf[4][2];
    #pragma unroll
    for (int m = 0; m < 4; ++m)
        #pragma unroll
        for (int ks = 0; ks < 2; ++ks)
            qf[m][ks] = *(const bf16x8*)&qb[(long)(q0 + m * 64 + w * 16 + r16) * 64 + ks * 32 + g * 8];

    f32x4 o[4][4] = {};
    float mr[4], lr[4];
    #pragma unroll
    for (int m = 0; m < 4; ++m) { mr[m] = -1e30f; lr[m] = 0.f; }

    const int T = (q0 >> 6) + 4;
    const char* kbyte = (const char*)kb;
    const char* vbyte = (const char*)vb;

    // stage tile 0
    {
        char* kdst = (char*)&K_lds[0][0][0];
        char* vdst = (char*)&V_lds[0][0][0];
        #pragma unroll
        for (int it = 0; it < 2; ++it) {
            long off = (long)tid * 16 + it * 4096;
            gload_lds16(kbyte + off, kdst + off);
            int cid = tid + (it << 8);
            gload_lds16(vbyte + (long)(cid >> 3) * 4096 + (cid & 7) * 16, vdst + cid * 16);
        }
    }

    for (int t = 0; t < T; ++t) {
        const int cur = t & 1;
        if (t + 1 < T) {
            const int jn = (t + 1) << 6;
            char* kdst = (char*)&K_lds[cur ^ 1][0][0];
            char* vdst = (char*)&V_lds[cur ^ 1][0][0];
            #pragma unroll
            for (int it = 0; it < 2; ++it) {
                long off = (long)tid * 16 + it * 4096;
                gload_lds16(kbyte + (long)jn * 128 + off, kdst + off);
                int cid = tid + (it << 8);
                gload_lds16(vbyte + (long)(cid >> 3) * 4096 + (long)jn * 2 + (cid & 7) * 16, vdst + cid * 16);
            }
        }
        __syncthreads();
        const int jt = t << 6;
        const char* kbase = (const char*)&K_lds[cur][0][0];
        const char* vbase = (const char*)&V_lds[cur][0][0];
        const int swz = (r16 & 7) << 4;

        #pragma unroll
        for (int m = 0; m < 4; ++m) {
            const int qbase = q0 + m * 64 + w * 16;
            if (jt > qbase + 15) continue;   // frag fully masked

            // S^T = K * Q : D[row=j][col=q]
            f32x4 s[4] = {};
            #pragma unroll
            for (int ks = 0; ks < 2; ++ks)
                #pragma unroll
                for (int n = 0; n < 4; ++n) {
                    bf16x8 kf = *(const bf16x8*)(kbase + (n * 16 + r16) * 128 + ((ks * 64 + g * 16) ^ swz));
                    s[n] = __builtin_amdgcn_mfma_f32_16x16x32_bf16(kf, qf[m][ks], s[n], 0, 0, 0);
                }
            if (jt + 63 > qbase) {           // diagonal: mask j > i
                const int i = qbase + r16;
                #pragma unroll
                for (int n = 0; n < 4; ++n)
                    #pragma unroll
                    for (int r = 0; r < 4; ++r)
                        if (jt + n * 16 + g * 4 + r > i) s[n][r] = -1e30f;
            }
            // row max: 16 in-lane + 2 shuffles (all 16 vals belong to q = r16)
            float tm = s[0][0];
            #pragma unroll
            for (int n = 0; n < 4; ++n)
                #pragma unroll
                for (int r = 0; r < 4; ++r)
                    tm = fmaxf(tm, s[n][r]);
            tm = fmaxf(tm, __shfl_xor(tm, 16));
            tm = fmaxf(tm, __shfl_xor(tm, 32));
            // defer-max (T13): rescale only when max grew past threshold
            if (__any(tm > mr[m] + 8.0f)) {
                float mn = fmaxf(mr[m], tm);
                float sc = __expf(mr[m] - mn);
                mr[m] = mn;
                lr[m] *= sc;
                float scr[4];
                #pragma unroll
                for (int r = 0; r < 4; ++r) scr[r] = __shfl(sc, (g << 2) + r);
                #pragma unroll
                for (int nd = 0; nd < 4; ++nd)
                    #pragma unroll
                    for (int r = 0; r < 4; ++r)
                        o[m][nd][r] *= scr[r];
            }
            // p = exp(s - m), sum, pack to P_lds
            float lsum = 0.f;
            #pragma unroll
            for (int n = 0; n < 4; ++n) {
                float p0 = __expf(s[n][0] - mr[m]);
                float p1 = __expf(s[n][1] - mr[m]);
                float p2 = __expf(s[n][2] - mr[m]);
                float p3 = __expf(s[n][3] - mr[m]);
                lsum += (p0 + p1) + (p2 + p3);
                short4 pk;
                pk.x = f2b(p0); pk.y = f2b(p1); pk.z = f2b(p2); pk.w = f2b(p3);
                *(short4*)&P_lds[w][r16][n * 16 + g * 4] = pk;
            }
            lsum += __shfl_xor(lsum, 16);
            lsum += __shfl_xor(lsum, 32);
            lr[m] += lsum;
            // PV: o[m][nd] += P[m] * V
            #pragma unroll
            for (int ks = 0; ks < 2; ++ks) {
                bf16x8 pf = *(const bf16x8*)&P_lds[w][r16][ks * 32 + g * 8];
                #pragma unroll
                for (int nd = 0; nd < 4; ++nd) {
                    bf16x8 vf = *(const bf16x8*)(vbase + (nd * 16 + r16) * 128 + ((ks * 64 + g * 16) ^ swz));
                    o[m][nd] = __builtin_amdgcn_mfma_f32_16x16x32_bf16(pf, vf, o[m][nd], 0, 0, 0);
                }
            }
        }
        __syncthreads();
    }

    const int b = bh >> 4, h = bh & 15;
    #pragma unroll
    for (int m = 0; m < 4; ++m) {
        float inv[4];
        #pragma unroll
        for (int r = 0; r < 4; ++r) inv[r] = 1.0f / __shfl(lr[m], (g << 2) + r);
        const int qb2 = q0 + m * 64 + w * 16 + (g << 2);
        #pragma unroll
        for (int nd = 0; nd < 4; ++nd)
            #pragma unroll
            for (int r = 0; r < 4; ++r)
                y[(long)(b * 2048 + qb2 + r) * 1024 + h * 64 + nd * 16 + r16] = f2b(o[m][nd][r] * inv[r]);
    }
}

extern "C" void kernel_launch(void* const* d_in, const int* in_sizes, int n_in,
                              void* d_out, int out_size, void* d_ws, size_t ws_size,
                              hipStream_t stream) {
    const float* x  = (const float*)d_in[0];
    const float* Wa = (const float*)d_in[1];
    const float* Wf = (const float*)d_in[2];
    float* out = (float*)d_out;
    char* ws = (char*)d_ws;
    short* xb  = (short*)(ws);                   // 16 MB (8192x1024 bf16); reused as y
    short* wab = (short*)(ws + (16l << 20));     // 6 MB  (3072x1024 bf16, transposed)
    short* wfb = (short*)(ws + (22l << 20));     // 2 MB  (1024x1024 bf16, transposed)
    short* qr  = (short*)(ws + (24l << 20));     // 16 MB [B,H,L,64] (pre-scaled by 1/8)
    short* kr  = (short*)(ws + (40l << 20));     // 16 MB [B,H,L,64] (d-swizzled)
    short* vt  = (short*)(ws + (56l << 20));     // 16 MB [B,H,64,L] (j-swizzled per 64-tile)

    conv_bf4<<<2048, 256, 0, stream>>>(x, xb, (long)8192 * 1024 / 4);
    transpose_bf<<<dim3(96, 32), dim3(32, 8), 0, stream>>>(Wa, wab, 1024, 3072);
    transpose_bf<<<dim3(32, 32), dim3(32, 8), 0, stream>>>(Wf, wfb, 1024, 1024);
    gemm_nt<0><<<dim3(24, 64), 256, 0, stream>>>(xb, wab, 8192, 3072, 1024, qr, kr, vt, nullptr);
    attn_kernel<<<512, 256, 0, stream>>>(qr, kr, vt, xb);
    gemm_nt<1><<<dim3(8, 64), 256, 0, stream>>>(xb, wfb, 8192, 1024, 1024, nullptr, nullptr, nullptr, out);
}

// Round 4
// 183.744 us; speedup vs baseline: 3.3095x; 1.3716x over previous
//
#include <hip/hip_runtime.h>
#include <hip/hip_bf16.h>

typedef __attribute__((ext_vector_type(8))) short bf16x8;
typedef __attribute__((ext_vector_type(4))) float f32x4;

__device__ __forceinline__ short f2b(float f) {
    unsigned u = __builtin_bit_cast(unsigned, f);
    unsigned r = (u + 0x7FFFu + ((u >> 16) & 1u)) >> 16;
    return (short)r;
}

__device__ __forceinline__ void gload_lds16(const void* g, void* l) {
    __builtin_amdgcn_global_load_lds((const __attribute__((address_space(1))) unsigned*)g,
                                     (__attribute__((address_space(3))) unsigned*)l, 16, 0, 0);
}

// ---------- convert x f32->bf16, k-chunk pre-swizzled (chunk^row&7 within 64-group) ----------
__global__ void conv_swz(const float* __restrict__ in, short* __restrict__ out, long nch) {
    long i = (long)blockIdx.x * blockDim.x + threadIdx.x;
    long stride = (long)gridDim.x * blockDim.x;
    for (; i < nch; i += stride) {
        long m = i >> 7;            // row (K=1024 -> 128 chunks of 8)
        int ch = (int)(i & 127);
        int p = (ch & ~7) | ((ch ^ (int)m) & 7);
        const float4* s = (const float4*)(in + i * 8);
        float4 a = s[0], b = s[1];
        bf16x8 ov;
        ov[0] = f2b(a.x); ov[1] = f2b(a.y); ov[2] = f2b(a.z); ov[3] = f2b(a.w);
        ov[4] = f2b(b.x); ov[5] = f2b(b.y); ov[6] = f2b(b.z); ov[7] = f2b(b.w);
        *(bf16x8*)(out + (m << 10) + p * 8) = ov;
    }
}

// ---------- transpose + convert + k-chunk pre-swizzle: in [R=K][C] f32 -> outT [C][K] bf16 ----------
__global__ void transpose_swz(const float* __restrict__ in, short* __restrict__ outT, int R, int C) {
    __shared__ float t[32][33];
    int c0 = blockIdx.x * 32, r0 = blockIdx.y * 32;
    int tx = threadIdx.x, ty = threadIdx.y; // 32 x 8
    #pragma unroll
    for (int j = 0; j < 4; ++j)
        t[ty + j * 8][tx] = in[(long)(r0 + ty + j * 8) * C + c0 + tx];
    __syncthreads();
    #pragma unroll
    for (int j = 0; j < 4; ++j) {
        int n = c0 + ty + j * 8;    // output row
        int k = r0 + tx;            // k index
        int kp = (k & ~63) | ((((k >> 3) ^ n) & 7) << 3) | (k & 7);
        outT[(long)n * R + kp] = f2b(t[tx][ty + j * 8]);
    }
}

// ---------- NT GEMM, m97 structure: BK=64, global_load_lds, swizzled ds_read ----------
// Inputs A,Bt must be k-chunk pre-swizzled (chunk ^ (row&7) within each 64-elem group).
template<int MODE>
__launch_bounds__(256, 2)
__global__ void gemm_nt(const short* __restrict__ A, const short* __restrict__ Bt,
                        int M, int N, int K,
                        short* __restrict__ qrole, short* __restrict__ krole,
                        short* __restrict__ vT, float* __restrict__ out) {
    __shared__ __align__(16) short As[128][64];
    __shared__ __align__(16) short Bs[128][64];
    const int tid = threadIdx.x;
    const int lane = tid & 63;
    const int wid = tid >> 6;
    const int wm = wid >> 1, wn = wid & 1;
    const int m0 = blockIdx.y * 128, n0 = blockIdx.x * 128;
    const int r16 = lane & 15, g = lane >> 4;
    const int sw = r16 & 7;
    const char* Ab = (const char*)A;
    const char* Bb = (const char*)Bt;
    const long Kb = (long)K * 2;
    f32x4 acc[4][4] = {};
    for (int k0 = 0; k0 < K; k0 += 64) {
        #pragma unroll
        for (int it = 0; it < 4; ++it) {
            int id = it * 256 + tid;      // 0..1023 chunk ids
            int r = id >> 3, cch = id & 7;
            gload_lds16(Ab + (long)(m0 + r) * Kb + k0 * 2 + cch * 16, (char*)As + id * 16);
            gload_lds16(Bb + (long)(n0 + r) * Kb + k0 * 2 + cch * 16, (char*)Bs + id * 16);
        }
        __syncthreads();
        #pragma unroll
        for (int kk = 0; kk < 2; ++kk) {
            bf16x8 af[4], bfr[4];
            #pragma unroll
            for (int m = 0; m < 4; ++m)
                af[m] = *(const bf16x8*)&As[wm * 64 + m * 16 + r16][((kk * 4 + g) ^ sw) * 8];
            #pragma unroll
            for (int n = 0; n < 4; ++n)
                bfr[n] = *(const bf16x8*)&Bs[wn * 64 + n * 16 + r16][((kk * 4 + g) ^ sw) * 8];
            #pragma unroll
            for (int m = 0; m < 4; ++m)
                #pragma unroll
                for (int n = 0; n < 4; ++n)
                    acc[m][n] = __builtin_amdgcn_mfma_f32_16x16x32_bf16(af[m], bfr[n], acc[m][n], 0, 0, 0);
        }
        __syncthreads();
    }
    #pragma unroll
    for (int m = 0; m < 4; ++m) {
        #pragma unroll
        for (int n = 0; n < 4; ++n) {
            #pragma unroll
            for (int r = 0; r < 4; ++r) {
                int row = m0 + wm * 64 + m * 16 + g * 4 + r;
                int col = n0 + wn * 64 + n * 16 + r16;
                float v = acc[m][n][r];
                if (MODE == 0) {
                    int which = col >> 10, cc = col & 1023;
                    int h = cc >> 6, d = cc & 63;
                    int b = row >> 11, li = row & 2047;
                    int bh = b * 16 + h;
                    if (which == 0)      qrole[((long)bh * 2048 + li) * 64 + d] = f2b(v * 0.125f);
                    else if (which == 1) krole[((long)bh * 2048 + li) * 64 + (d ^ ((li & 7) << 3))] = f2b(v);
                    else                 vT[((long)bh * 64 + d) * 2048 + ((li & ~63) | ((li & 63) ^ ((d & 7) << 3)))] = f2b(v);
                } else {
                    out[(long)row * N + col] = v;
                }
            }
        }
    }
}

// ---------- flash attention: paired 128-row chunks (uniform work), overlapped staging ----------
__launch_bounds__(256, 2)
__global__ void attn_kernel(const short* __restrict__ qrole, const short* __restrict__ krole,
                            const short* __restrict__ vT, short* __restrict__ y) {
    __shared__ __align__(16) short K_lds[2][64][64];
    __shared__ __align__(16) short V_lds[2][64][64];
    __shared__ __align__(16) short P_lds[4][16][72];
    const int tid = threadIdx.x, lane = tid & 63, w = tid >> 6;
    const int r16 = lane & 15, g = lane >> 4;
    const int idb = blockIdx.x;
    const int bh = idb & 63;           // id%8 == bh%8 -> one XCD per bh
    const int pr = idb >> 6;           // 0..3: chunk pair (pr, 15-pr)
    const short* qb = qrole + (long)bh * (2048 * 64);
    const char* kbyte = (const char*)(krole + (long)bh * (2048 * 64));
    const char* vbyte = (const char*)(vT + (long)bh * (64 * 2048));
    const int b = bh >> 4, h = bh & 15;

    #pragma unroll
    for (int cc = 0; cc < 2; ++cc) {
        const int c = cc ? (15 - pr) : pr;   // 128-row chunk index
        const int q0 = c << 7;
        const int T = 2 * c + 2;

        bf16x8 qf[2][2];
        #pragma unroll
        for (int m = 0; m < 2; ++m)
            #pragma unroll
            for (int ks = 0; ks < 2; ++ks)
                qf[m][ks] = *(const bf16x8*)&qb[(long)(q0 + m * 64 + w * 16 + r16) * 64 + ks * 32 + g * 8];

        f32x4 o[2][4] = {};
        float mr[2], lr[2];
        #pragma unroll
        for (int m = 0; m < 2; ++m) { mr[m] = -1e30f; lr[m] = 0.f; }

        if (cc) __syncthreads();   // protect LDS reuse across chunks
        // stage tile 0 into buf 0
        {
            char* kdst = (char*)&K_lds[0][0][0];
            char* vdst = (char*)&V_lds[0][0][0];
            #pragma unroll
            for (int it = 0; it < 2; ++it) {
                int cid = it * 256 + tid;
                long r = cid >> 3; int cch = cid & 7;
                gload_lds16(kbyte + r * 128 + cch * 16, kdst + cid * 16);
                gload_lds16(vbyte + r * 4096 + cch * 16, vdst + cid * 16);
            }
        }

        for (int t = 0; t < T; ++t) {
            __syncthreads();               // stage(t) landed; prev compute done
            const int cur = t & 1;
            if (t + 1 < T) {               // issue stage(t+1): hidden under compute(t)
                const long jn = (long)(t + 1) << 6;
                char* kdst = (char*)&K_lds[cur ^ 1][0][0];
                char* vdst = (char*)&V_lds[cur ^ 1][0][0];
                #pragma unroll
                for (int it = 0; it < 2; ++it) {
                    int cid = it * 256 + tid;
                    long r = cid >> 3; int cch = cid & 7;
                    gload_lds16(kbyte + (jn + r) * 128 + cch * 16, kdst + cid * 16);
                    gload_lds16(vbyte + r * 4096 + jn * 2 + cch * 16, vdst + cid * 16);
                }
            }
            const int jt = t << 6;
            const char* kbase = (const char*)&K_lds[cur][0][0];
            const char* vbase = (const char*)&V_lds[cur][0][0];
            const int swz = (r16 & 7) << 4;

            #pragma unroll
            for (int m = 0; m < 2; ++m) {
                const int qbase = q0 + m * 64 + w * 16;
                if (jt > qbase + 15) continue;   // frag fully masked

                // S^T = K * Q
                f32x4 s[4] = {};
                #pragma unroll
                for (int ks = 0; ks < 2; ++ks)
                    #pragma unroll
                    for (int n = 0; n < 4; ++n) {
                        bf16x8 kf = *(const bf16x8*)(kbase + (n * 16 + r16) * 128 + ((ks * 64 + g * 16) ^ swz));
                        s[n] = __builtin_amdgcn_mfma_f32_16x16x32_bf16(kf, qf[m][ks], s[n], 0, 0, 0);
                    }
                if (jt + 63 > qbase) {           // diagonal: mask j > i
                    const int i = qbase + r16;
                    #pragma unroll
                    for (int n = 0; n < 4; ++n)
                        #pragma unroll
                        for (int r = 0; r < 4; ++r)
                            if (jt + n * 16 + g * 4 + r > i) s[n][r] = -1e30f;
                }
                // row max: in-lane + 2 shuffles
                float tm = s[0][0];
                #pragma unroll
                for (int n = 0; n < 4; ++n)
                    #pragma unroll
                    for (int r = 0; r < 4; ++r)
                        tm = fmaxf(tm, s[n][r]);
                tm = fmaxf(tm, __shfl_xor(tm, 16));
                tm = fmaxf(tm, __shfl_xor(tm, 32));
                // defer-max (T13)
                if (__any(tm > mr[m] + 8.0f)) {
                    float mn = fmaxf(mr[m], tm);
                    float sc = __expf(mr[m] - mn);
                    mr[m] = mn;
                    lr[m] *= sc;
                    float scr[4];
                    #pragma unroll
                    for (int r = 0; r < 4; ++r) scr[r] = __shfl(sc, (g << 2) + r);
                    #pragma unroll
                    for (int nd = 0; nd < 4; ++nd)
                        #pragma unroll
                        for (int r = 0; r < 4; ++r)
                            o[m][nd][r] *= scr[r];
                }
                // p = exp(s - m), local sum, pack to P_lds
                float lsum = 0.f;
                #pragma unroll
                for (int n = 0; n < 4; ++n) {
                    float p0 = __expf(s[n][0] - mr[m]);
                    float p1 = __expf(s[n][1] - mr[m]);
                    float p2 = __expf(s[n][2] - mr[m]);
                    float p3 = __expf(s[n][3] - mr[m]);
                    lsum += (p0 + p1) + (p2 + p3);
                    short4 pk;
                    pk.x = f2b(p0); pk.y = f2b(p1); pk.z = f2b(p2); pk.w = f2b(p3);
                    *(short4*)&P_lds[w][r16][n * 16 + g * 4] = pk;
                }
                lsum += __shfl_xor(lsum, 16);
                lsum += __shfl_xor(lsum, 32);
                lr[m] += lsum;
                // PV
                #pragma unroll
                for (int ks = 0; ks < 2; ++ks) {
                    bf16x8 pf = *(const bf16x8*)&P_lds[w][r16][ks * 32 + g * 8];
                    #pragma unroll
                    for (int nd = 0; nd < 4; ++nd) {
                        bf16x8 vf = *(const bf16x8*)(vbase + (nd * 16 + r16) * 128 + ((ks * 64 + g * 16) ^ swz));
                        o[m][nd] = __builtin_amdgcn_mfma_f32_16x16x32_bf16(pf, vf, o[m][nd], 0, 0, 0);
                    }
                }
            }
        }
        // epilogue: write y with GEMM2's k-chunk pre-swizzle
        #pragma unroll
        for (int m = 0; m < 2; ++m) {
            float inv[4];
            #pragma unroll
            for (int r = 0; r < 4; ++r) inv[r] = 1.0f / __shfl(lr[m], (g << 2) + r);
            const int li0 = q0 + m * 64 + w * 16 + (g << 2);
            #pragma unroll
            for (int nd = 0; nd < 4; ++nd)
                #pragma unroll
                for (int r = 0; r < 4; ++r) {
                    int li = li0 + r;
                    int sub = ((nd * 2 + (r16 >> 3)) ^ li) & 7;
                    int kp = h * 64 + sub * 8 + (r16 & 7);
                    y[(long)(b * 2048 + li) * 1024 + kp] = f2b(o[m][nd][r] * inv[r]);
                }
        }
    }
}

extern "C" void kernel_launch(void* const* d_in, const int* in_sizes, int n_in,
                              void* d_out, int out_size, void* d_ws, size_t ws_size,
                              hipStream_t stream) {
    const float* x  = (const float*)d_in[0];
    const float* Wa = (const float*)d_in[1];
    const float* Wf = (const float*)d_in[2];
    float* out = (float*)d_out;
    char* ws = (char*)d_ws;
    short* xb  = (short*)(ws);                   // 16 MB (8192x1024 bf16, pre-swz); reused as y
    short* wab = (short*)(ws + (16l << 20));     // 6 MB  (3072x1024 bf16, T + pre-swz)
    short* wfb = (short*)(ws + (22l << 20));     // 2 MB  (1024x1024 bf16, T + pre-swz)
    short* qr  = (short*)(ws + (24l << 20));     // 16 MB [B,H,L,64] (pre-scaled by 1/8)
    short* kr  = (short*)(ws + (40l << 20));     // 16 MB [B,H,L,64] (d-swizzled)
    short* vt  = (short*)(ws + (56l << 20));     // 16 MB [B,H,64,L] (j-swizzled per 64-tile)

    conv_swz<<<2048, 256, 0, stream>>>(x, xb, (long)8192 * 128);
    transpose_swz<<<dim3(96, 32), dim3(32, 8), 0, stream>>>(Wa, wab, 1024, 3072);
    transpose_swz<<<dim3(32, 32), dim3(32, 8), 0, stream>>>(Wf, wfb, 1024, 1024);
    gemm_nt<0><<<dim3(24, 64), 256, 0, stream>>>(xb, wab, 8192, 3072, 1024, qr, kr, vt, nullptr);
    attn_kernel<<<512, 256, 0, stream>>>(qr, kr, vt, xb);
    gemm_nt<1><<<dim3(8, 64), 256, 0, stream>>>(xb, wfb, 8192, 1024, 1024, nullptr, nullptr, nullptr, out);
}

// Round 5
// 179.129 us; speedup vs baseline: 3.3948x; 1.0258x over previous
//
#include <hip/hip_runtime.h>
#include <hip/hip_bf16.h>

typedef __attribute__((ext_vector_type(8))) short bf16x8;
typedef __attribute__((ext_vector_type(4))) float f32x4;

__device__ __forceinline__ short f2b(float f) {
    unsigned u = __builtin_bit_cast(unsigned, f);
    unsigned r = (u + 0x7FFFu + ((u >> 16) & 1u)) >> 16;
    return (short)r;
}

__device__ __forceinline__ unsigned cvt_pk_bf16(float lo, float hi) {
    unsigned r;
    asm("v_cvt_pk_bf16_f32 %0, %1, %2" : "=v"(r) : "v"(lo), "v"(hi));
    return r;
}

__device__ __forceinline__ void gload_lds16(const void* g, void* l) {
    __builtin_amdgcn_global_load_lds((const __attribute__((address_space(1))) unsigned*)g,
                                     (__attribute__((address_space(3))) unsigned*)l, 16, 0, 0);
}

// ---------- convert x f32->bf16, k-chunk pre-swizzled (chunk^row&7 within 64-group) ----------
__global__ void conv_swz(const float* __restrict__ in, short* __restrict__ out, long nch) {
    long i = (long)blockIdx.x * blockDim.x + threadIdx.x;
    long stride = (long)gridDim.x * blockDim.x;
    for (; i < nch; i += stride) {
        long m = i >> 7;            // row (K=1024 -> 128 chunks of 8)
        int ch = (int)(i & 127);
        int p = (ch & ~7) | ((ch ^ (int)m) & 7);
        const float4* s = (const float4*)(in + i * 8);
        float4 a = s[0], b = s[1];
        bf16x8 ov;
        ov[0] = f2b(a.x); ov[1] = f2b(a.y); ov[2] = f2b(a.z); ov[3] = f2b(a.w);
        ov[4] = f2b(b.x); ov[5] = f2b(b.y); ov[6] = f2b(b.z); ov[7] = f2b(b.w);
        *(bf16x8*)(out + (m << 10) + p * 8) = ov;
    }
}

// ---------- transpose + convert + k-chunk pre-swizzle: in [R=K][C] f32 -> outT [C][K] bf16 ----------
__global__ void transpose_swz(const float* __restrict__ in, short* __restrict__ outT, int R, int C) {
    __shared__ float t[32][33];
    int c0 = blockIdx.x * 32, r0 = blockIdx.y * 32;
    int tx = threadIdx.x, ty = threadIdx.y; // 32 x 8
    #pragma unroll
    for (int j = 0; j < 4; ++j)
        t[ty + j * 8][tx] = in[(long)(r0 + ty + j * 8) * C + c0 + tx];
    __syncthreads();
    #pragma unroll
    for (int j = 0; j < 4; ++j) {
        int n = c0 + ty + j * 8;    // output row
        int k = r0 + tx;            // k index
        int kp = (k & ~63) | ((((k >> 3) ^ n) & 7) << 3) | (k & 7);
        outT[(long)n * R + kp] = f2b(t[tx][ty + j * 8]);
    }
}

// ---------- NT GEMM, m97 structure: BK=64, global_load_lds, swizzled ds_read ----------
// Inputs A,Bt must be k-chunk pre-swizzled (chunk ^ (row&7) within each 64-elem group).
template<int MODE>
__launch_bounds__(256, 2)
__global__ void gemm_nt(const short* __restrict__ A, const short* __restrict__ Bt,
                        int M, int N, int K,
                        short* __restrict__ qrole, short* __restrict__ krole,
                        short* __restrict__ vT, float* __restrict__ out) {
    __shared__ __align__(16) short As[128][64];
    __shared__ __align__(16) short Bs[128][64];
    const int tid = threadIdx.x;
    const int lane = tid & 63;
    const int wid = tid >> 6;
    const int wm = wid >> 1, wn = wid & 1;
    const int m0 = blockIdx.y * 128, n0 = blockIdx.x * 128;
    const int r16 = lane & 15, g = lane >> 4;
    const int sw = r16 & 7;
    const char* Ab = (const char*)A;
    const char* Bb = (const char*)Bt;
    const long Kb = (long)K * 2;
    f32x4 acc[4][4] = {};
    for (int k0 = 0; k0 < K; k0 += 64) {
        #pragma unroll
        for (int it = 0; it < 4; ++it) {
            int id = it * 256 + tid;      // 0..1023 chunk ids
            int r = id >> 3, cch = id & 7;
            gload_lds16(Ab + (long)(m0 + r) * Kb + k0 * 2 + cch * 16, (char*)As + id * 16);
            gload_lds16(Bb + (long)(n0 + r) * Kb + k0 * 2 + cch * 16, (char*)Bs + id * 16);
        }
        __syncthreads();
        #pragma unroll
        for (int kk = 0; kk < 2; ++kk) {
            bf16x8 af[4], bfr[4];
            #pragma unroll
            for (int m = 0; m < 4; ++m)
                af[m] = *(const bf16x8*)&As[wm * 64 + m * 16 + r16][((kk * 4 + g) ^ sw) * 8];
            #pragma unroll
            for (int n = 0; n < 4; ++n)
                bfr[n] = *(const bf16x8*)&Bs[wn * 64 + n * 16 + r16][((kk * 4 + g) ^ sw) * 8];
            #pragma unroll
            for (int m = 0; m < 4; ++m)
                #pragma unroll
                for (int n = 0; n < 4; ++n)
                    acc[m][n] = __builtin_amdgcn_mfma_f32_16x16x32_bf16(af[m], bfr[n], acc[m][n], 0, 0, 0);
        }
        __syncthreads();
    }
    #pragma unroll
    for (int m = 0; m < 4; ++m) {
        #pragma unroll
        for (int n = 0; n < 4; ++n) {
            #pragma unroll
            for (int r = 0; r < 4; ++r) {
                int row = m0 + wm * 64 + m * 16 + g * 4 + r;
                int col = n0 + wn * 64 + n * 16 + r16;
                float v = acc[m][n][r];
                if (MODE == 0) {
                    int which = col >> 10, cc = col & 1023;
                    int h = cc >> 6, d = cc & 63;
                    int b = row >> 11, li = row & 2047;
                    int bh = b * 16 + h;
                    // q pre-scaled by (1/8)*log2(e) -> softmax runs in exp2 domain
                    if (which == 0)      qrole[((long)bh * 2048 + li) * 64 + d] = f2b(v * 0.18033688f);
                    else if (which == 1) krole[((long)bh * 2048 + li) * 64 + (d ^ ((li & 7) << 3))] = f2b(v);
                    else                 vT[((long)bh * 64 + d) * 2048 + ((li & ~63) | ((li & 63) ^ ((d & 7) << 3)))] = f2b(v);
                } else {
                    out[(long)row * N + col] = v;
                }
            }
        }
    }
}

// ---------- flash attention: one 128-row chunk per block, LPT, exp2-domain softmax ----------
__launch_bounds__(256, 3)
__global__ void attn_kernel(const short* __restrict__ qrole, const short* __restrict__ krole,
                            const short* __restrict__ vT, short* __restrict__ y) {
    __shared__ __align__(16) short K_lds[2][64][64];
    __shared__ __align__(16) short V_lds[2][64][64];
    __shared__ __align__(16) short P_lds[4][16][72];
    const int tid = threadIdx.x, lane = tid & 63, w = tid >> 6;
    const int r16 = lane & 15, g = lane >> 4;
    const int idb = blockIdx.x;
    const int bh = idb & 63;           // id%8 == bh%8 -> one XCD per bh
    const int c = 15 - (idb >> 6);     // chunk (128 q-rows); LPT: big c dispatched first
    const int q0 = c << 7;
    const int T = 2 * c + 2;
    const short* qb = qrole + (long)bh * (2048 * 64);
    const char* kbyte = (const char*)(krole + (long)bh * (2048 * 64));
    const char* vbyte = (const char*)(vT + (long)bh * (64 * 2048));
    const int b = bh >> 4, h = bh & 15;

    bf16x8 qf[2][2];
    #pragma unroll
    for (int m = 0; m < 2; ++m)
        #pragma unroll
        for (int ks = 0; ks < 2; ++ks)
            qf[m][ks] = *(const bf16x8*)&qb[(long)(q0 + m * 64 + w * 16 + r16) * 64 + ks * 32 + g * 8];

    f32x4 o[2][4] = {};
    float mr[2], lr[2];
    #pragma unroll
    for (int m = 0; m < 2; ++m) { mr[m] = -1e30f; lr[m] = 0.f; }

    // stage tile 0 into buf 0
    {
        char* kdst = (char*)&K_lds[0][0][0];
        char* vdst = (char*)&V_lds[0][0][0];
        #pragma unroll
        for (int it = 0; it < 2; ++it) {
            int cid = it * 256 + tid;
            long r = cid >> 3; int cch = cid & 7;
            gload_lds16(kbyte + r * 128 + cch * 16, kdst + cid * 16);
            gload_lds16(vbyte + r * 4096 + cch * 16, vdst + cid * 16);
        }
    }

    for (int t = 0; t < T; ++t) {
        __syncthreads();               // stage(t) landed; prev compute done
        const int cur = t & 1;
        if (t + 1 < T) {               // issue stage(t+1): hidden under compute(t)
            const long jn = (long)(t + 1) << 6;
            char* kdst = (char*)&K_lds[cur ^ 1][0][0];
            char* vdst = (char*)&V_lds[cur ^ 1][0][0];
            #pragma unroll
            for (int it = 0; it < 2; ++it) {
                int cid = it * 256 + tid;
                long r = cid >> 3; int cch = cid & 7;
                gload_lds16(kbyte + (jn + r) * 128 + cch * 16, kdst + cid * 16);
                gload_lds16(vbyte + r * 4096 + jn * 2 + cch * 16, vdst + cid * 16);
            }
        }
        const int jt = t << 6;
        const char* kbase = (const char*)&K_lds[cur][0][0];
        const char* vbase = (const char*)&V_lds[cur][0][0];
        const int swz = (r16 & 7) << 4;

        #pragma unroll
        for (int m = 0; m < 2; ++m) {
            const int qbase = q0 + m * 64 + w * 16;
            if (jt > qbase + 15) continue;   // frag fully masked

            // S^T = K * Q (exp2 domain: q pre-scaled by log2e/8)
            f32x4 s[4] = {};
            #pragma unroll
            for (int ks = 0; ks < 2; ++ks)
                #pragma unroll
                for (int n = 0; n < 4; ++n) {
                    bf16x8 kf = *(const bf16x8*)(kbase + (n * 16 + r16) * 128 + ((ks * 64 + g * 16) ^ swz));
                    s[n] = __builtin_amdgcn_mfma_f32_16x16x32_bf16(kf, qf[m][ks], s[n], 0, 0, 0);
                }
            if (jt + 63 > qbase) {           // diagonal: mask j > i
                const int i = qbase + r16;
                #pragma unroll
                for (int n = 0; n < 4; ++n)
                    #pragma unroll
                    for (int r = 0; r < 4; ++r)
                        if (jt + n * 16 + g * 4 + r > i) s[n][r] = -1e30f;
            }
            // row max: in-lane + 2 shuffles
            float tm = s[0][0];
            #pragma unroll
            for (int n = 0; n < 4; ++n)
                #pragma unroll
                for (int r = 0; r < 4; ++r)
                    tm = fmaxf(tm, s[n][r]);
            tm = fmaxf(tm, __shfl_xor(tm, 16));
            tm = fmaxf(tm, __shfl_xor(tm, 32));
            // defer-max (T13), log2 units: 11.5 ~= 8 nats -> P <= 2^11.5
            if (__any(tm > mr[m] + 11.5f)) {
                float mn = fmaxf(mr[m], tm);
                float sc = exp2f(mr[m] - mn);
                mr[m] = mn;
                lr[m] *= sc;
                float scr[4];
                #pragma unroll
                for (int r = 0; r < 4; ++r) scr[r] = __shfl(sc, (g << 2) + r);
                #pragma unroll
                for (int nd = 0; nd < 4; ++nd)
                    #pragma unroll
                    for (int r = 0; r < 4; ++r)
                        o[m][nd][r] *= scr[r];
            }
            // p = exp2(s - m), local sum, cvt_pk pack -> P_lds (b64 per n)
            float lsum = 0.f;
            #pragma unroll
            for (int n = 0; n < 4; ++n) {
                float p0 = exp2f(s[n][0] - mr[m]);
                float p1 = exp2f(s[n][1] - mr[m]);
                float p2 = exp2f(s[n][2] - mr[m]);
                float p3 = exp2f(s[n][3] - mr[m]);
                lsum += (p0 + p1) + (p2 + p3);
                unsigned w0 = cvt_pk_bf16(p0, p1);
                unsigned w1 = cvt_pk_bf16(p2, p3);
                unsigned long long dw = ((unsigned long long)w1 << 32) | w0;
                *(unsigned long long*)&P_lds[w][r16][n * 16 + g * 4] = dw;
            }
            lsum += __shfl_xor(lsum, 16);
            lsum += __shfl_xor(lsum, 32);
            lr[m] += lsum;
            // PV
            #pragma unroll
            for (int ks = 0; ks < 2; ++ks) {
                bf16x8 pf = *(const bf16x8*)&P_lds[w][r16][ks * 32 + g * 8];
                #pragma unroll
                for (int nd = 0; nd < 4; ++nd) {
                    bf16x8 vf = *(const bf16x8*)(vbase + (nd * 16 + r16) * 128 + ((ks * 64 + g * 16) ^ swz));
                    o[m][nd] = __builtin_amdgcn_mfma_f32_16x16x32_bf16(pf, vf, o[m][nd], 0, 0, 0);
                }
            }
        }
    }
    // epilogue: write y with GEMM2's k-chunk pre-swizzle
    #pragma unroll
    for (int m = 0; m < 2; ++m) {
        float inv[4];
        #pragma unroll
        for (int r = 0; r < 4; ++r) inv[r] = 1.0f / __shfl(lr[m], (g << 2) + r);
        const int li0 = q0 + m * 64 + w * 16 + (g << 2);
        #pragma unroll
        for (int nd = 0; nd < 4; ++nd)
            #pragma unroll
            for (int r = 0; r < 4; ++r) {
                int li = li0 + r;
                int sub = ((nd * 2 + (r16 >> 3)) ^ li) & 7;
                int kp = h * 64 + sub * 8 + (r16 & 7);
                y[(long)(b * 2048 + li) * 1024 + kp] = f2b(o[m][nd][r] * inv[r]);
            }
    }
}

extern "C" void kernel_launch(void* const* d_in, const int* in_sizes, int n_in,
                              void* d_out, int out_size, void* d_ws, size_t ws_size,
                              hipStream_t stream) {
    const float* x  = (const float*)d_in[0];
    const float* Wa = (const float*)d_in[1];
    const float* Wf = (const float*)d_in[2];
    float* out = (float*)d_out;
    char* ws = (char*)d_ws;
    short* xb  = (short*)(ws);                   // 16 MB (8192x1024 bf16, pre-swz); reused as y
    short* wab = (short*)(ws + (16l << 20));     // 6 MB  (3072x1024 bf16, T + pre-swz)
    short* wfb = (short*)(ws + (22l << 20));     // 2 MB  (1024x1024 bf16, T + pre-swz)
    short* qr  = (short*)(ws + (24l << 20));     // 16 MB [B,H,L,64] (pre-scaled by log2e/8)
    short* kr  = (short*)(ws + (40l << 20));     // 16 MB [B,H,L,64] (d-swizzled)
    short* vt  = (short*)(ws + (56l << 20));     // 16 MB [B,H,64,L] (j-swizzled per 64-tile)

    conv_swz<<<2048, 256, 0, stream>>>(x, xb, (long)8192 * 128);
    transpose_swz<<<dim3(96, 32), dim3(32, 8), 0, stream>>>(Wa, wab, 1024, 3072);
    transpose_swz<<<dim3(32, 32), dim3(32, 8), 0, stream>>>(Wf, wfb, 1024, 1024);
    gemm_nt<0><<<dim3(24, 64), 256, 0, stream>>>(xb, wab, 8192, 3072, 1024, qr, kr, vt, nullptr);
    attn_kernel<<<1024, 256, 0, stream>>>(qr, kr, vt, xb);
    gemm_nt<1><<<dim3(8, 64), 256, 0, stream>>>(xb, wfb, 8192, 1024, 1024, nullptr, nullptr, nullptr, out);
}

// Round 6
// 174.526 us; speedup vs baseline: 3.4843x; 1.0264x over previous
//
#include <hip/hip_runtime.h>
#include <hip/hip_bf16.h>

typedef __attribute__((ext_vector_type(8))) short bf16x8;
typedef __attribute__((ext_vector_type(4))) float f32x4;

__device__ __forceinline__ short f2b(float f) {
    unsigned u = __builtin_bit_cast(unsigned, f);
    unsigned r = (u + 0x7FFFu + ((u >> 16) & 1u)) >> 16;
    return (short)r;
}

__device__ __forceinline__ unsigned cvt_pk_bf16(float lo, float hi) {
    unsigned r;
    asm("v_cvt_pk_bf16_f32 %0, %1, %2" : "=v"(r) : "v"(lo), "v"(hi));
    return r;
}

__device__ __forceinline__ float fexp2(float x) {
    float r;
    asm("v_exp_f32 %0, %1" : "=v"(r) : "v"(x));
    return r;
}

__device__ __forceinline__ void gload_lds16(const void* g, void* l) {
    __builtin_amdgcn_global_load_lds((const __attribute__((address_space(1))) unsigned*)g,
                                     (__attribute__((address_space(3))) unsigned*)l, 16, 0, 0);
}

// ---------- convert x f32->bf16, k-chunk pre-swizzled (chunk^row&7 within 64-group) ----------
__global__ void conv_swz(const float* __restrict__ in, short* __restrict__ out, long nch) {
    long i = (long)blockIdx.x * blockDim.x + threadIdx.x;
    long stride = (long)gridDim.x * blockDim.x;
    for (; i < nch; i += stride) {
        long m = i >> 7;            // row (K=1024 -> 128 chunks of 8)
        int ch = (int)(i & 127);
        int p = (ch & ~7) | ((ch ^ (int)m) & 7);
        const float4* s = (const float4*)(in + i * 8);
        float4 a = s[0], b = s[1];
        bf16x8 ov;
        ov[0] = f2b(a.x); ov[1] = f2b(a.y); ov[2] = f2b(a.z); ov[3] = f2b(a.w);
        ov[4] = f2b(b.x); ov[5] = f2b(b.y); ov[6] = f2b(b.z); ov[7] = f2b(b.w);
        *(bf16x8*)(out + (m << 10) + p * 8) = ov;
    }
}

// ---------- transpose + convert + k-chunk pre-swizzle: in [R=K][C] f32 -> outT [C][K] bf16 ----------
__global__ void transpose_swz(const float* __restrict__ in, short* __restrict__ outT, int R, int C) {
    __shared__ float t[32][33];
    int c0 = blockIdx.x * 32, r0 = blockIdx.y * 32;
    int tx = threadIdx.x, ty = threadIdx.y; // 32 x 8
    #pragma unroll
    for (int j = 0; j < 4; ++j)
        t[ty + j * 8][tx] = in[(long)(r0 + ty + j * 8) * C + c0 + tx];
    __syncthreads();
    #pragma unroll
    for (int j = 0; j < 4; ++j) {
        int n = c0 + ty + j * 8;    // output row
        int k = r0 + tx;            // k index
        int kp = (k & ~63) | ((((k >> 3) ^ n) & 7) << 3) | (k & 7);
        outT[(long)n * R + kp] = f2b(t[tx][ty + j * 8]);
    }
}

// ---------- NT GEMM, m97 structure: BK=64, global_load_lds, swizzled ds_read ----------
template<int MODE>
__launch_bounds__(256, 4)
__global__ void gemm_nt(const short* __restrict__ A, const short* __restrict__ Bt,
                        int M, int N, int K,
                        short* __restrict__ qrole, short* __restrict__ krole,
                        short* __restrict__ vT, float* __restrict__ out) {
    __shared__ __align__(16) short As[128][64];
    __shared__ __align__(16) short Bs[128][64];
    const int tid = threadIdx.x;
    const int lane = tid & 63;
    const int wid = tid >> 6;
    const int wm = wid >> 1, wn = wid & 1;
    const int m0 = blockIdx.y * 128, n0 = blockIdx.x * 128;
    const int r16 = lane & 15, g = lane >> 4;
    const int sw = r16 & 7;
    const char* Ab = (const char*)A;
    const char* Bb = (const char*)Bt;
    const long Kb = (long)K * 2;
    f32x4 acc[4][4] = {};
    for (int k0 = 0; k0 < K; k0 += 64) {
        #pragma unroll
        for (int it = 0; it < 4; ++it) {
            int id = it * 256 + tid;      // 0..1023 chunk ids
            int r = id >> 3, cch = id & 7;
            gload_lds16(Ab + (long)(m0 + r) * Kb + k0 * 2 + cch * 16, (char*)As + id * 16);
            gload_lds16(Bb + (long)(n0 + r) * Kb + k0 * 2 + cch * 16, (char*)Bs + id * 16);
        }
        __syncthreads();
        #pragma unroll
        for (int kk = 0; kk < 2; ++kk) {
            bf16x8 af[4], bfr[4];
            #pragma unroll
            for (int m = 0; m < 4; ++m)
                af[m] = *(const bf16x8*)&As[wm * 64 + m * 16 + r16][((kk * 4 + g) ^ sw) * 8];
            #pragma unroll
            for (int n = 0; n < 4; ++n)
                bfr[n] = *(const bf16x8*)&Bs[wn * 64 + n * 16 + r16][((kk * 4 + g) ^ sw) * 8];
            #pragma unroll
            for (int m = 0; m < 4; ++m)
                #pragma unroll
                for (int n = 0; n < 4; ++n)
                    acc[m][n] = __builtin_amdgcn_mfma_f32_16x16x32_bf16(af[m], bfr[n], acc[m][n], 0, 0, 0);
        }
        __syncthreads();
    }
    #pragma unroll
    for (int m = 0; m < 4; ++m) {
        #pragma unroll
        for (int n = 0; n < 4; ++n) {
            #pragma unroll
            for (int r = 0; r < 4; ++r) {
                int row = m0 + wm * 64 + m * 16 + g * 4 + r;
                int col = n0 + wn * 64 + n * 16 + r16;
                float v = acc[m][n][r];
                if (MODE == 0) {
                    int which = col >> 10, cc = col & 1023;
                    int h = cc >> 6, d = cc & 63;
                    int b = row >> 11, li = row & 2047;
                    int bh = b * 16 + h;
                    // q pre-scaled by (1/8)*log2(e) -> softmax runs in exp2 domain
                    if (which == 0)      qrole[((long)bh * 2048 + li) * 64 + d] = f2b(v * 0.18033688f);
                    else if (which == 1) krole[((long)bh * 2048 + li) * 64 + (d ^ ((li & 7) << 3))] = f2b(v);
                    else                 vT[((long)bh * 64 + d) * 2048 + ((li & ~63) | ((li & 63) ^ ((d & 7) << 3)))] = f2b(v);
                } else {
                    out[(long)row * N + col] = v;
                }
            }
        }
    }
}

// ---------- flash attention: 1 chunk (128 q-rows)/block, balanced c-map, 4 blocks/CU ----------
__launch_bounds__(256, 4)
__global__ void attn_kernel(const short* __restrict__ qrole, const short* __restrict__ krole,
                            const short* __restrict__ vT, short* __restrict__ y) {
    __shared__ __align__(16) short K_lds[2][64][64];
    __shared__ __align__(16) short V_lds[2][64][64];
    __shared__ __align__(16) short P_lds[4][16][64];
    const int tid = threadIdx.x, lane = tid & 63, w = tid >> 6;
    const int r16 = lane & 15, g = lane >> 4;
    const int idb = blockIdx.x;
    const int bh = idb & 63;           // id%8 == bh%8 -> one XCD per bh (KV L2-resident)
    const int u = idb >> 8;            // 0..3 dispatch batch
    const int a = (idb >> 6) & 3;      // 0..3
    // per-CU quartet {15-a, a, 11-a, 4+a} sums to 30 -> uniform 68 tiles/CU; big-first
    const int c = (u == 0) ? (15 - a) : (u == 1) ? a : (u == 2) ? (11 - a) : (4 + a);
    const int q0 = c << 7;
    const int T = 2 * c + 2;
    const short* qb = qrole + (long)bh * (2048 * 64);
    const char* kbyte = (const char*)(krole + (long)bh * (2048 * 64));
    const char* vbyte = (const char*)(vT + (long)bh * (64 * 2048));
    const int b = bh >> 4, h = bh & 15;

    bf16x8 qf[2][2];
    #pragma unroll
    for (int m = 0; m < 2; ++m)
        #pragma unroll
        for (int ks = 0; ks < 2; ++ks)
            qf[m][ks] = *(const bf16x8*)&qb[(long)(q0 + m * 64 + w * 16 + r16) * 64 + ks * 32 + g * 8];

    f32x4 o[2][4] = {};
    float mr[2], lr[2];
    #pragma unroll
    for (int m = 0; m < 2; ++m) { mr[m] = -1e30f; lr[m] = 0.f; }

    // per-thread staging source pointers (advance by constants per tile)
    const int rr = tid >> 3, cch = tid & 7;
    const char* kg0 = kbyte + rr * 128 + cch * 16;            // rows 0..31
    const char* kg1 = kbyte + (32 + rr) * 128 + cch * 16;     // rows 32..63
    const char* vg0 = vbyte + rr * 4096 + cch * 16;
    const char* vg1 = vbyte + (32 + rr) * 4096 + cch * 16;
    char* Kb_ = (char*)&K_lds[0][0][0];
    char* Vb_ = (char*)&V_lds[0][0][0];
    const int ld0 = tid * 16, ld1 = (256 + tid) * 16;

    // stage tile 0 into buf 0
    gload_lds16(kg0, Kb_ + ld0);
    gload_lds16(kg1, Kb_ + ld1);
    gload_lds16(vg0, Vb_ + ld0);
    gload_lds16(vg1, Vb_ + ld1);

    const int psw = (r16 & 7) << 4;
    char* prow = (char*)&P_lds[w][r16][0];

    for (int t = 0; t < T; ++t) {
        __syncthreads();               // stage(t) landed (vmcnt drain) + all waves synced
        const int cur = t & 1;
        if (t + 1 < T) {               // issue stage(t+1), lands by next barrier
            long adv = (long)(t + 1) * 8192;
            long advv = (long)(t + 1) * 128;
            char* kdst = Kb_ + (cur ^ 1) * 8192;
            char* vdst = Vb_ + (cur ^ 1) * 8192;
            gload_lds16(kg0 + adv, kdst + ld0);
            gload_lds16(kg1 + adv, kdst + ld1);
            gload_lds16(vg0 + advv, vdst + ld0);
            gload_lds16(vg1 + advv, vdst + ld1);
        }
        const int jt = t << 6;
        const char* kbase = Kb_ + cur * 8192;
        const char* vbase = Vb_ + cur * 8192;

        #pragma unroll
        for (int m = 0; m < 2; ++m) {
            const int qbase = q0 + m * 64 + w * 16;
            if (jt > qbase + 15) continue;   // frag fully masked (wave-uniform)

            // S^T = K * Q (exp2 domain)
            f32x4 s[4] = {};
            __builtin_amdgcn_s_setprio(1);
            #pragma unroll
            for (int ks = 0; ks < 2; ++ks)
                #pragma unroll
                for (int n = 0; n < 4; ++n) {
                    bf16x8 kf = *(const bf16x8*)(kbase + (n * 16 + r16) * 128 + ((ks * 64 + g * 16) ^ psw));
                    s[n] = __builtin_amdgcn_mfma_f32_16x16x32_bf16(kf, qf[m][ks], s[n], 0, 0, 0);
                }
            __builtin_amdgcn_s_setprio(0);
            if (jt + 63 > qbase) {           // diagonal: mask j > i
                const int i = qbase + r16;
                #pragma unroll
                for (int n = 0; n < 4; ++n)
                    #pragma unroll
                    for (int r = 0; r < 4; ++r)
                        if (jt + n * 16 + g * 4 + r > i) s[n][r] = -1e30f;
            }
            // row max, tree (fmax->max3 fusion)
            float t0 = fmaxf(fmaxf(s[0][0], s[0][1]), fmaxf(s[0][2], s[0][3]));
            float t1 = fmaxf(fmaxf(s[1][0], s[1][1]), fmaxf(s[1][2], s[1][3]));
            float t2 = fmaxf(fmaxf(s[2][0], s[2][1]), fmaxf(s[2][2], s[2][3]));
            float t3 = fmaxf(fmaxf(s[3][0], s[3][1]), fmaxf(s[3][2], s[3][3]));
            float tm = fmaxf(fmaxf(t0, t1), fmaxf(t2, t3));
            tm = fmaxf(tm, __shfl_xor(tm, 16));
            tm = fmaxf(tm, __shfl_xor(tm, 32));
            // defer-max (T13), log2 units (11.5 ~= 8 nats)
            if (__any(tm > mr[m] + 11.5f)) {
                float mn = fmaxf(mr[m], tm);
                float sc = fexp2(mr[m] - mn);
                mr[m] = mn;
                lr[m] *= sc;
                float scr[4];
                #pragma unroll
                for (int r = 0; r < 4; ++r) scr[r] = __shfl(sc, (g << 2) + r);
                #pragma unroll
                for (int nd = 0; nd < 4; ++nd)
                    #pragma unroll
                    for (int r = 0; r < 4; ++r)
                        o[m][nd][r] *= scr[r];
            }
            // p = exp2(s - m), tree sum, cvt_pk pack -> swizzled P_lds
            float p[4][4];
            #pragma unroll
            for (int n = 0; n < 4; ++n) {
                p[n][0] = fexp2(s[n][0] - mr[m]);
                p[n][1] = fexp2(s[n][1] - mr[m]);
                p[n][2] = fexp2(s[n][2] - mr[m]);
                p[n][3] = fexp2(s[n][3] - mr[m]);
                unsigned w0 = cvt_pk_bf16(p[n][0], p[n][1]);
                unsigned w1 = cvt_pk_bf16(p[n][2], p[n][3]);
                unsigned long long dw = ((unsigned long long)w1 << 32) | w0;
                *(unsigned long long*)(prow + ((n * 32 + g * 8) ^ psw)) = dw;
            }
            float l0 = (p[0][0] + p[0][1]) + (p[0][2] + p[0][3]);
            float l1 = (p[1][0] + p[1][1]) + (p[1][2] + p[1][3]);
            float l2 = (p[2][0] + p[2][1]) + (p[2][2] + p[2][3]);
            float l3 = (p[3][0] + p[3][1]) + (p[3][2] + p[3][3]);
            float lsum = (l0 + l1) + (l2 + l3);
            lsum += __shfl_xor(lsum, 16);
            lsum += __shfl_xor(lsum, 32);
            lr[m] += lsum;
            // PV
            __builtin_amdgcn_s_setprio(1);
            #pragma unroll
            for (int ks = 0; ks < 2; ++ks) {
                bf16x8 pf = *(const bf16x8*)(prow + ((ks * 64 + g * 16) ^ psw));
                #pragma unroll
                for (int nd = 0; nd < 4; ++nd) {
                    bf16x8 vf = *(const bf16x8*)(vbase + (nd * 16 + r16) * 128 + ((ks * 64 + g * 16) ^ psw));
                    o[m][nd] = __builtin_amdgcn_mfma_f32_16x16x32_bf16(pf, vf, o[m][nd], 0, 0, 0);
                }
            }
            __builtin_amdgcn_s_setprio(0);
        }
    }
    // epilogue: write y with GEMM2's k-chunk pre-swizzle
    #pragma unroll
    for (int m = 0; m < 2; ++m) {
        float inv[4];
        #pragma unroll
        for (int r = 0; r < 4; ++r) inv[r] = 1.0f / __shfl(lr[m], (g << 2) + r);
        const int li0 = q0 + m * 64 + w * 16 + (g << 2);
        #pragma unroll
        for (int nd = 0; nd < 4; ++nd)
            #pragma unroll
            for (int r = 0; r < 4; ++r) {
                int li = li0 + r;
                int sub = ((nd * 2 + (r16 >> 3)) ^ li) & 7;
                int kp = h * 64 + sub * 8 + (r16 & 7);
                y[(long)(b * 2048 + li) * 1024 + kp] = f2b(o[m][nd][r] * inv[r]);
            }
    }
}

extern "C" void kernel_launch(void* const* d_in, const int* in_sizes, int n_in,
                              void* d_out, int out_size, void* d_ws, size_t ws_size,
                              hipStream_t stream) {
    const float* x  = (const float*)d_in[0];
    const float* Wa = (const float*)d_in[1];
    const float* Wf = (const float*)d_in[2];
    float* out = (float*)d_out;
    char* ws = (char*)d_ws;
    short* xb  = (short*)(ws);                   // 16 MB (8192x1024 bf16, pre-swz); reused as y
    short* wab = (short*)(ws + (16l << 20));     // 6 MB  (3072x1024 bf16, T + pre-swz)
    short* wfb = (short*)(ws + (22l << 20));     // 2 MB  (1024x1024 bf16, T + pre-swz)
    short* qr  = (short*)(ws + (24l << 20));     // 16 MB [B,H,L,64] (pre-scaled by log2e/8)
    short* kr  = (short*)(ws + (40l << 20));     // 16 MB [B,H,L,64] (d-swizzled)
    short* vt  = (short*)(ws + (56l << 20));     // 16 MB [B,H,64,L] (j-swizzled per 64-tile)

    conv_swz<<<2048, 256, 0, stream>>>(x, xb, (long)8192 * 128);
    transpose_swz<<<dim3(96, 32), dim3(32, 8), 0, stream>>>(Wa, wab, 1024, 3072);
    transpose_swz<<<dim3(32, 32), dim3(32, 8), 0, stream>>>(Wf, wfb, 1024, 1024);
    gemm_nt<0><<<dim3(24, 64), 256, 0, stream>>>(xb, wab, 8192, 3072, 1024, qr, kr, vt, nullptr);
    attn_kernel<<<1024, 256, 0, stream>>>(qr, kr, vt, xb);
    gemm_nt<1><<<dim3(8, 64), 256, 0, stream>>>(xb, wfb, 8192, 1024, 1024, nullptr, nullptr, nullptr, out);
}